// Round 2
// baseline (234.759 us; speedup 1.0000x reference)
//
#include <hip/hip_runtime.h>
#include <hip/hip_bf16.h>
#include <math.h>

// Problem geometry (B=2, T=1024, D=384 -> d=128, D3=384, D9=1152)
#define NTOK  2048
#define DD    128
#define DD3   384
#define DD9   1152
#define TB    8          // tokens per block in fused kernel
#define GAMMA_F 5.0f

// Workspace layout in floats:
//  [0, 147456)            : SWq,SWk,SWv  (3 x 384x128, softplus(W), layout [j][i])
//  [147456, 589824)       : WpT          (384 x 1152, WpT[i][o] = softplus(Wp[o][i]))
//  [589824, 737280)       : Mq,Mk,Mv     (3 x 128x384, M[i][m] = sum_j SW[j][i]*S[j][m])
//  [737280, 738432)       : cq,ck,cv     (3 x 384,     c[m] = sum_j b[j]*S[j][m])
#define OFF_SW   0
#define OFF_WPT  147456
#define OFF_M    589824
#define OFF_C    737280

__device__ __forceinline__ float softplusf(float x) {
    // log1p(exp(x)) computed stably
    return fmaxf(x, 0.0f) + log1pf(__expf(-fabsf(x)));
}

// ---------------- prep 0: elementwise softplus of Wq/Wk/Wv and transposed softplus(Wp)
__global__ void k_prep_sp(const float* __restrict__ Wq, const float* __restrict__ Wk,
                          const float* __restrict__ Wv, const float* __restrict__ Wp,
                          float* __restrict__ ws) {
    int idx = blockIdx.x * blockDim.x + threadIdx.x;   // 0 .. 589823
    if (idx < 3 * 49152) {
        const float* W = (idx < 49152) ? Wq : (idx < 2 * 49152 ? Wk : Wv);
        int k = idx % 49152;
        ws[OFF_SW + idx] = softplusf(W[k]);
    } else {
        int j = idx - 3 * 49152;                        // 0 .. 442367 -> (i, o)
        if (j < DD3 * DD9) {
            int i = j / DD9, o = j % DD9;
            ws[OFF_WPT + j] = softplusf(Wp[o * DD3 + i]);
        }
    }
}

// ---------------- prep 1: M[i][m] = sum_j SW[j][i] * S[j][m]   (3 matrices, 8 i-rows per block)
__global__ void k_prep_M(const float* __restrict__ Sq, const float* __restrict__ Sk,
                         const float* __restrict__ Sv, float* __restrict__ ws) {
    __shared__ float sw[DD3 * 8];
    int mat = blockIdx.x >> 4;          // 0..2
    int i0  = (blockIdx.x & 15) * 8;    // 0..120
    const float* SW = ws + OFF_SW + mat * 49152;
    const float* S  = (mat == 0) ? Sq : (mat == 1 ? Sk : Sv);
    float* M = ws + OFF_M + mat * 49152;

    for (int idx = threadIdx.x; idx < DD3 * 8; idx += DD3) {
        int j = idx >> 3, ii = idx & 7;
        sw[idx] = SW[j * DD + i0 + ii];
    }
    __syncthreads();

    int m = threadIdx.x;
    float acc[8];
#pragma unroll
    for (int ii = 0; ii < 8; ++ii) acc[ii] = 0.0f;
    for (int j = 0; j < DD3; ++j) {
        float s = S[j * DD3 + m];
#pragma unroll
        for (int ii = 0; ii < 8; ++ii) acc[ii] = fmaf(sw[j * 8 + ii], s, acc[ii]);
    }
#pragma unroll
    for (int ii = 0; ii < 8; ++ii) M[(i0 + ii) * DD3 + m] = acc[ii];
}

// ---------------- prep 2: c[m] = sum_j b[j] * S[j][m]
__global__ void k_prep_c(const float* __restrict__ Sq, const float* __restrict__ Sk,
                         const float* __restrict__ Sv, const float* __restrict__ bq,
                         const float* __restrict__ bk, const float* __restrict__ bv,
                         float* __restrict__ ws) {
    int mat = blockIdx.x;
    const float* S = (mat == 0) ? Sq : (mat == 1 ? Sk : Sv);
    const float* b = (mat == 0) ? bq : (mat == 1 ? bk : bv);
    int m = threadIdx.x;
    float acc = 0.0f;
    for (int j = 0; j < DD3; ++j) acc = fmaf(b[j], S[j * DD3 + m], acc);
    ws[OFF_C + mat * DD3 + m] = acc;
}

// ---------------- fused main: QKV projection -> sigmoid attention -> Wp projection -> LayerNorm
__global__ __launch_bounds__(384) void k_fused(const float* __restrict__ x,
                                               const float* __restrict__ bp,
                                               const float* __restrict__ gn,
                                               const float* __restrict__ bn,
                                               const float* __restrict__ ws,
                                               float* __restrict__ out) {
    __shared__ float xs[TB * DD3];        // 12 KB
    __shared__ float qkv[3 * TB * DD3];   // 36 KB  (Q | K | V, each [TB][384])
    __shared__ float att[TB * DD3];       // 12 KB
    __shared__ float red[16];

    int tid = threadIdx.x;                // 0..383
    int tok0 = blockIdx.x * TB;

    // stage x tile
    for (int idx = tid; idx < TB * DD3; idx += DD3)
        xs[idx] = x[(size_t)tok0 * DD3 + idx];
    __syncthreads();

    // phase 2: Q/K/V[t][m] = c[m] + sum_i xs[t][mat*128 + i] * M[i][m]
    const float* M0 = ws + OFF_M;
    const float* c0 = ws + OFF_C;
#pragma unroll
    for (int mat = 0; mat < 3; ++mat) {
        const float* M = M0 + mat * 49152;
        float c = c0[mat * DD3 + tid];
        float acc[TB];
#pragma unroll
        for (int t = 0; t < TB; ++t) acc[t] = c;
        for (int i = 0; i < DD; ++i) {
            float mv = M[i * DD3 + tid];
#pragma unroll
            for (int t = 0; t < TB; ++t)
                acc[t] = fmaf(xs[t * DD3 + mat * DD + i], mv, acc[t]);
        }
#pragma unroll
        for (int t = 0; t < TB; ++t) qkv[(mat * TB + t) * DD3 + tid] = acc[t];
    }
    __syncthreads();

    // phase 3: per-token sigmoid attention; thread `tid` owns row i=tid
    for (int t = 0; t < TB; ++t) {
        float q = GAMMA_F * qkv[t * DD3 + tid];
        const float* K = &qkv[(TB + t) * DD3];
        const float* V = &qkv[(2 * TB + t) * DD3];
        float rs = 0.0f, acc = 0.0f;
#pragma unroll 4
        for (int j = 0; j < DD3; ++j) {
            float e = __expf(-q * K[j]);                       // v_exp
            float s = __builtin_amdgcn_rcpf(1.0f + e);         // v_rcp: sigmoid
            rs += s;
            acc = fmaf(s, V[j], acc);
        }
        att[t * DD3 + tid] = acc * __builtin_amdgcn_rcpf(rs + 1e-8f);
    }
    __syncthreads();

    // phase 4: h[t][o] = bp[o] + sum_i att[t][i] * WpT[i][o]; o = tid + r*384, kept in regs
    const float* WpT = ws + OFF_WPT;
    float acc[3][TB];
#pragma unroll
    for (int r = 0; r < 3; ++r) {
        float b = bp[tid + r * DD3];
#pragma unroll
        for (int t = 0; t < TB; ++t) acc[r][t] = b;
    }
    for (int i = 0; i < DD3; ++i) {
        float w0 = WpT[i * DD9 + tid];
        float w1 = WpT[i * DD9 + tid + DD3];
        float w2 = WpT[i * DD9 + tid + 2 * DD3];
#pragma unroll
        for (int t = 0; t < TB; ++t) {
            float a = att[t * DD3 + i];
            acc[0][t] = fmaf(a, w0, acc[0][t]);
            acc[1][t] = fmaf(a, w1, acc[1][t]);
            acc[2][t] = fmaf(a, w2, acc[2][t]);
        }
    }

    // phase 5: TWO-PASS LayerNorm per token over 1152 (avoids E[h^2]-mu^2 cancellation:
    // h has |mu|/sigma ~ 90 here, single-pass var loses ~5% -> 0.2 output error)
    for (int t = 0; t < TB; ++t) {
        float v0 = acc[0][t], v1 = acc[1][t], v2 = acc[2][t];
        int wave = tid >> 6, lane = tid & 63;

        // pass 1: mean
        float s1 = v0 + v1 + v2;
#pragma unroll
        for (int off = 32; off; off >>= 1) s1 += __shfl_down(s1, off, 64);
        if (lane == 0) red[wave] = s1;
        __syncthreads();
        if (tid == 0) {
            float a = 0.0f;
            for (int w = 0; w < 6; ++w) a += red[w];
            red[14] = a * (1.0f / 1152.0f);
        }
        __syncthreads();
        float mu = red[14];

        // pass 2: variance of deviations
        float d0 = v0 - mu, d1 = v1 - mu, d2 = v2 - mu;
        float s2 = fmaf(d0, d0, fmaf(d1, d1, d2 * d2));
#pragma unroll
        for (int off = 32; off; off >>= 1) s2 += __shfl_down(s2, off, 64);
        if (lane == 0) red[8 + wave] = s2;
        __syncthreads();
        if (tid == 0) {
            float b = 0.0f;
            for (int w = 0; w < 6; ++w) b += red[8 + w];
            float var = b * (1.0f / 1152.0f);
            red[15] = __builtin_amdgcn_rsqf(var + 1e-5f);
        }
        __syncthreads();
        float inv = red[15];

        size_t base = (size_t)(tok0 + t) * DD9;
        out[base + tid]           = fmaf(d0 * inv, gn[tid],           bn[tid]);
        out[base + tid + DD3]     = fmaf(d1 * inv, gn[tid + DD3],     bn[tid + DD3]);
        out[base + tid + 2 * DD3] = fmaf(d2 * inv, gn[tid + 2 * DD3], bn[tid + 2 * DD3]);
        __syncthreads();
    }
}

extern "C" void kernel_launch(void* const* d_in, const int* in_sizes, int n_in,
                              void* d_out, int out_size, void* d_ws, size_t ws_size,
                              hipStream_t stream) {
    const float* x  = (const float*)d_in[0];
    const float* Wq = (const float*)d_in[1];
    const float* bq = (const float*)d_in[2];
    const float* Sq = (const float*)d_in[3];
    const float* Wk = (const float*)d_in[4];
    const float* bk = (const float*)d_in[5];
    const float* Sk = (const float*)d_in[6];
    const float* Wv = (const float*)d_in[7];
    const float* bv = (const float*)d_in[8];
    const float* Sv = (const float*)d_in[9];
    const float* Wp = (const float*)d_in[10];
    const float* bp = (const float*)d_in[11];
    const float* gn = (const float*)d_in[12];
    const float* bn = (const float*)d_in[13];
    float* out = (float*)d_out;
    float* ws  = (float*)d_ws;

    // prep: 589824 elems total = 2304 * 256 exactly
    hipLaunchKernelGGL(k_prep_sp, dim3(2304), dim3(256), 0, stream, Wq, Wk, Wv, Wp, ws);
    hipLaunchKernelGGL(k_prep_M,  dim3(48),   dim3(384), 0, stream, Sq, Sk, Sv, ws);
    hipLaunchKernelGGL(k_prep_c,  dim3(3),    dim3(384), 0, stream, Sq, Sk, Sv, bq, bk, bv, ws);
    // fused main: 2048 tokens / 8 per block = 256 blocks
    hipLaunchKernelGGL(k_fused, dim3(NTOK / TB), dim3(384), 0, stream, x, bp, gn, bn, ws, out);
}

// Round 4
// 215.318 us; speedup vs baseline: 1.0903x; 1.0903x over previous
//
#include <hip/hip_runtime.h>
#include <hip/hip_bf16.h>
#include <math.h>

// Problem geometry (B=2, T=1024, D=384 -> d=128, D3=384, D9=1152)
#define NTOK  2048
#define DD    128
#define DD3   384
#define DD9   1152
#define TB    4          // tokens per block in fused kernel -> 512 blocks = 2/CU
#define GAMMA_F 5.0f
#define LN2_F 0.69314718f

// Workspace layout (float units):
//  OFF_M  : Mq,Mk,Mv  (3 x 128x384 fp32)   M[i][m] = sum_j softplus(W[j][i]) * S[j][m]
//  OFF_C  : cq,ck,cv  (3 x 384 fp32)       c[m]    = sum_j b[j] * S[j][m]
//  OFF_WP4: WpT delta-packed bf16x4 (384x384 ushort4):
//           [i][m] = {sp(i,m)-ln2, sp(i,m+384)-ln2, sp(i,m+768)-ln2, 0}, sp(i,o)=softplus(Wp[o][i])
#define OFF_M    0
#define OFF_C    147456
#define OFF_WP4  148608   // 147456 ushort4 = 294912 floats

__device__ __forceinline__ float softplusf(float x) {
    return fmaxf(x, 0.0f) + log1pf(__expf(-fabsf(x)));   // stable log1p(exp(x))
}
__device__ __forceinline__ float bf2f(unsigned short u) {
    return __uint_as_float(((unsigned)u) << 16);
}
__device__ __forceinline__ unsigned short f2bf(float f) {
    __hip_bfloat16 h = __float2bfloat16(f);              // RNE
    return *reinterpret_cast<unsigned short*>(&h);
}

// ---------------- prep A: delta-packed bf16 Wp table. idx -> (i, m)
__global__ void k_wpt4(const float* __restrict__ Wp, float* __restrict__ ws) {
    int idx = blockIdx.x * blockDim.x + threadIdx.x;     // 0..147455 (grid exact)
    int i = idx / DD3, m = idx % DD3;
    ushort4 u;
    u.x = f2bf(softplusf(Wp[(0 * DD3 + m) * DD3 + i]) - LN2_F);
    u.y = f2bf(softplusf(Wp[(1 * DD3 + m) * DD3 + i]) - LN2_F);
    u.z = f2bf(softplusf(Wp[(2 * DD3 + m) * DD3 + i]) - LN2_F);
    u.w = 0;
    ((ushort4*)(ws + OFF_WP4))[idx] = u;
}

// ---------------- prep B: M[i][m] = sum_j softplus(W[j][i]) * S[j][m]; one (mat,i) per block
__global__ __launch_bounds__(384) void k_prep_M(const float* __restrict__ Wq, const float* __restrict__ Wk,
                                                const float* __restrict__ Wv, const float* __restrict__ Sq,
                                                const float* __restrict__ Sk, const float* __restrict__ Sv,
                                                float* __restrict__ ws) {
    __shared__ float sw[DD3];
    int mat = blockIdx.x >> 7;          // 0..2
    int i   = blockIdx.x & 127;         // 0..127
    const float* W = (mat == 0) ? Wq : (mat == 1 ? Wk : Wv);
    const float* S = (mat == 0) ? Sq : (mat == 1 ? Sk : Sv);
    int m = threadIdx.x;
    sw[m] = softplusf(W[m * DD + i]);   // j = threadIdx.x
    __syncthreads();
    const float4* sw4 = (const float4*)sw;
    float a0 = 0.f, a1 = 0.f, a2 = 0.f, a3 = 0.f;
    for (int j4 = 0; j4 < 96; ++j4) {
        float4 w = sw4[j4];
        int j = j4 * 4;
        a0 = fmaf(w.x, S[(j + 0) * DD3 + m], a0);
        a1 = fmaf(w.y, S[(j + 1) * DD3 + m], a1);
        a2 = fmaf(w.z, S[(j + 2) * DD3 + m], a2);
        a3 = fmaf(w.w, S[(j + 3) * DD3 + m], a3);
    }
    ws[OFF_M + mat * 49152 + i * DD3 + m] = (a0 + a1) + (a2 + a3);
}

// ---------------- prep C: c[m] = sum_j b[j] * S[j][m]
__global__ __launch_bounds__(384) void k_prep_c(const float* __restrict__ Sq, const float* __restrict__ Sk,
                                                const float* __restrict__ Sv, const float* __restrict__ bq,
                                                const float* __restrict__ bk, const float* __restrict__ bv,
                                                float* __restrict__ ws) {
    int mat = blockIdx.x;
    const float* S = (mat == 0) ? Sq : (mat == 1 ? Sk : Sv);
    const float* b = (mat == 0) ? bq : (mat == 1 ? bk : bv);
    int m = threadIdx.x;
    float a0 = 0.f, a1 = 0.f, a2 = 0.f, a3 = 0.f;
    for (int j4 = 0; j4 < 96; ++j4) {
        int j = j4 * 4;
        a0 = fmaf(b[j + 0], S[(j + 0) * DD3 + m], a0);
        a1 = fmaf(b[j + 1], S[(j + 1) * DD3 + m], a1);
        a2 = fmaf(b[j + 2], S[(j + 2) * DD3 + m], a2);
        a3 = fmaf(b[j + 3], S[(j + 3) * DD3 + m], a3);
    }
    ws[OFF_C + mat * DD3 + m] = (a0 + a1) + (a2 + a3);
}

// ---------------- fused main: QKV projection -> sigmoid attention -> Wp projection -> 2-pass LN
__global__ __launch_bounds__(384, 3) void k_fused(const float* __restrict__ x,
                                                  const float* __restrict__ bp,
                                                  const float* __restrict__ gn,
                                                  const float* __restrict__ bn,
                                                  const float* __restrict__ ws,
                                                  float* __restrict__ out) {
    __shared__ float xs[TB * DD3];          // 6 KB
    __shared__ float qkv[3 * TB * DD3];     // 18 KB  (Q | K | V, each [TB][384])
    __shared__ float att[TB * DD3];         // 6 KB
    __shared__ float red[32];
    __shared__ float smu[TB], sinv[TB];

    int tid = threadIdx.x;                  // 0..383
    int tok0 = blockIdx.x * TB;

    // stage x tile: 1536 floats = 384 x float4
    ((float4*)xs)[tid] = ((const float4*)(x + (size_t)tok0 * DD3))[tid];
    __syncthreads();

    // phase 2: Q/K/V[t][m] = c[m] + sum_i xs[t][mat*128 + i] * M[i][m]
    const float4* xs4 = (const float4*)xs;
#pragma unroll
    for (int mat = 0; mat < 3; ++mat) {
        const float* M = ws + OFF_M + mat * 49152;
        float acc0 = 0.f, acc1 = 0.f, acc2 = 0.f, acc3 = 0.f;
        for (int i4 = 0; i4 < 32; ++i4) {
            int i = i4 * 4;
            float m0 = M[(i + 0) * DD3 + tid];
            float m1 = M[(i + 1) * DD3 + tid];
            float m2 = M[(i + 2) * DD3 + tid];
            float m3 = M[(i + 3) * DD3 + tid];
            float4 x0 = xs4[0 * 96 + mat * 32 + i4];
            float4 x1 = xs4[1 * 96 + mat * 32 + i4];
            float4 x2 = xs4[2 * 96 + mat * 32 + i4];
            float4 x3 = xs4[3 * 96 + mat * 32 + i4];
            acc0 = fmaf(x0.x, m0, fmaf(x0.y, m1, fmaf(x0.z, m2, fmaf(x0.w, m3, acc0))));
            acc1 = fmaf(x1.x, m0, fmaf(x1.y, m1, fmaf(x1.z, m2, fmaf(x1.w, m3, acc1))));
            acc2 = fmaf(x2.x, m0, fmaf(x2.y, m1, fmaf(x2.z, m2, fmaf(x2.w, m3, acc2))));
            acc3 = fmaf(x3.x, m0, fmaf(x3.y, m1, fmaf(x3.z, m2, fmaf(x3.w, m3, acc3))));
        }
        float c = ws[OFF_C + mat * DD3 + tid];
        qkv[(mat * TB + 0) * DD3 + tid] = acc0 + c;
        qkv[(mat * TB + 1) * DD3 + tid] = acc1 + c;
        qkv[(mat * TB + 2) * DD3 + tid] = acc2 + c;
        qkv[(mat * TB + 3) * DD3 + tid] = acc3 + c;
    }
    __syncthreads();

    // phase 3: sigmoid attention, thread owns row i=tid; float4 K/V reads, 16 exp chains in flight
    float nq[TB], rs[TB], av[TB];
#pragma unroll
    for (int t = 0; t < TB; ++t) {
        nq[t] = -GAMMA_F * qkv[t * DD3 + tid];
        rs[t] = 0.f; av[t] = 0.f;
    }
    const float4* qkv4 = (const float4*)qkv;
    for (int j4 = 0; j4 < 96; ++j4) {
#pragma unroll
        for (int t = 0; t < TB; ++t) {
            float4 k4 = qkv4[(TB + t) * 96 + j4];
            float4 v4 = qkv4[(2 * TB + t) * 96 + j4];
            float s0 = __builtin_amdgcn_rcpf(1.0f + __expf(nq[t] * k4.x));
            float s1 = __builtin_amdgcn_rcpf(1.0f + __expf(nq[t] * k4.y));
            float s2 = __builtin_amdgcn_rcpf(1.0f + __expf(nq[t] * k4.z));
            float s3 = __builtin_amdgcn_rcpf(1.0f + __expf(nq[t] * k4.w));
            rs[t] += (s0 + s1) + (s2 + s3);
            av[t] = fmaf(s0, v4.x, fmaf(s1, v4.y, fmaf(s2, v4.z, fmaf(s3, v4.w, av[t]))));
        }
    }
#pragma unroll
    for (int t = 0; t < TB; ++t)
        att[t * DD3 + tid] = av[t] * __builtin_amdgcn_rcpf(rs[t] + 1e-8f);
    __syncthreads();

    // phase 4: h[t][o] = bp[o] + sum_i att[t][i] * (ln2 + delta[i][o]); o = tid + r*384 in regs
    const ushort4* wp4 = (const ushort4*)(ws + OFF_WP4);
    float acc[3][TB];
#pragma unroll
    for (int r = 0; r < 3; ++r) {
        float b = bp[tid + r * DD3];
#pragma unroll
        for (int t = 0; t < TB; ++t) acc[r][t] = b;
    }
    const float4* att4 = (const float4*)att;
    for (int i4 = 0; i4 < 96; ++i4) {
        float4 a0 = att4[0 * 96 + i4];
        float4 a1 = att4[1 * 96 + i4];
        float4 a2 = att4[2 * 96 + i4];
        float4 a3 = att4[3 * 96 + i4];
        const float* af0 = (const float*)&a0;
        const float* af1 = (const float*)&a1;
        const float* af2 = (const float*)&a2;
        const float* af3 = (const float*)&a3;
#pragma unroll
        for (int e = 0; e < 4; ++e) {
            ushort4 w = wp4[(i4 * 4 + e) * DD3 + tid];
            float w0 = LN2_F + bf2f(w.x);
            float w1 = LN2_F + bf2f(w.y);
            float w2 = LN2_F + bf2f(w.z);
            acc[0][0] = fmaf(af0[e], w0, acc[0][0]);
            acc[1][0] = fmaf(af0[e], w1, acc[1][0]);
            acc[2][0] = fmaf(af0[e], w2, acc[2][0]);
            acc[0][1] = fmaf(af1[e], w0, acc[0][1]);
            acc[1][1] = fmaf(af1[e], w1, acc[1][1]);
            acc[2][1] = fmaf(af1[e], w2, acc[2][1]);
            acc[0][2] = fmaf(af2[e], w0, acc[0][2]);
            acc[1][2] = fmaf(af2[e], w1, acc[1][2]);
            acc[2][2] = fmaf(af2[e], w2, acc[2][2]);
            acc[0][3] = fmaf(af3[e], w0, acc[0][3]);
            acc[1][3] = fmaf(af3[e], w1, acc[1][3]);
            acc[2][3] = fmaf(af3[e], w2, acc[2][3]);
        }
    }

    // phase 5: two-pass LayerNorm (mu first; then var of deviations)
    int wave = tid >> 6, lane = tid & 63;
#pragma unroll
    for (int t = 0; t < TB; ++t) {
        float s = acc[0][t] + acc[1][t] + acc[2][t];
#pragma unroll
        for (int off = 32; off; off >>= 1) s += __shfl_down(s, off, 64);
        if (lane == 0) red[t * 8 + wave] = s;
    }
    __syncthreads();
    if (tid < TB) {
        float a = 0.f;
        for (int w = 0; w < 6; ++w) a += red[tid * 8 + w];
        smu[tid] = a * (1.0f / 1152.0f);
    }
    __syncthreads();
#pragma unroll
    for (int t = 0; t < TB; ++t) {
        float mu = smu[t];
        acc[0][t] -= mu; acc[1][t] -= mu; acc[2][t] -= mu;
        float s = fmaf(acc[0][t], acc[0][t], fmaf(acc[1][t], acc[1][t], acc[2][t] * acc[2][t]));
#pragma unroll
        for (int off = 32; off; off >>= 1) s += __shfl_down(s, off, 64);
        if (lane == 0) red[t * 8 + wave] = s;
    }
    __syncthreads();
    if (tid < TB) {
        float b = 0.f;
        for (int w = 0; w < 6; ++w) b += red[tid * 8 + w];
        sinv[tid] = __builtin_amdgcn_rsqf(b * (1.0f / 1152.0f) + 1e-5f);
    }
    __syncthreads();
    float g0 = gn[tid], g1 = gn[tid + DD3], g2 = gn[tid + 2 * DD3];
    float b0 = bn[tid], b1 = bn[tid + DD3], b2 = bn[tid + 2 * DD3];
#pragma unroll
    for (int t = 0; t < TB; ++t) {
        float inv = sinv[t];
        size_t base = (size_t)(tok0 + t) * DD9;
        out[base + tid]           = fmaf(acc[0][t] * inv, g0, b0);
        out[base + tid + DD3]     = fmaf(acc[1][t] * inv, g1, b1);
        out[base + tid + 2 * DD3] = fmaf(acc[2][t] * inv, g2, b2);
    }
}

extern "C" void kernel_launch(void* const* d_in, const int* in_sizes, int n_in,
                              void* d_out, int out_size, void* d_ws, size_t ws_size,
                              hipStream_t stream) {
    const float* x  = (const float*)d_in[0];
    const float* Wq = (const float*)d_in[1];
    const float* bq = (const float*)d_in[2];
    const float* Sq = (const float*)d_in[3];
    const float* Wk = (const float*)d_in[4];
    const float* bk = (const float*)d_in[5];
    const float* Sk = (const float*)d_in[6];
    const float* Wv = (const float*)d_in[7];
    const float* bv = (const float*)d_in[8];
    const float* Sv = (const float*)d_in[9];
    const float* Wp = (const float*)d_in[10];
    const float* bp = (const float*)d_in[11];
    const float* gn = (const float*)d_in[12];
    const float* bn = (const float*)d_in[13];
    float* out = (float*)d_out;
    float* ws  = (float*)d_ws;

    hipLaunchKernelGGL(k_wpt4,  dim3(576), dim3(256), 0, stream, Wp, ws);            // 147456 threads exact
    hipLaunchKernelGGL(k_prep_M, dim3(384), dim3(384), 0, stream, Wq, Wk, Wv, Sq, Sk, Sv, ws);
    hipLaunchKernelGGL(k_prep_c, dim3(3),   dim3(384), 0, stream, Sq, Sk, Sv, bq, bk, bv, ws);
    hipLaunchKernelGGL(k_fused, dim3(NTOK / TB), dim3(384), 0, stream, x, bp, gn, bn, ws, out);
}

// Round 5
// 159.410 us; speedup vs baseline: 1.4727x; 1.3507x over previous
//
#include <hip/hip_runtime.h>
#include <hip/hip_bf16.h>
#include <math.h>

// Problem geometry (B=2, T=1024, D=384 -> d=128, D3=384, D9=1152)
#define NTOK  2048
#define DD    128
#define DD3   384
#define DD9   1152
#define TB    4          // tokens per block -> 512 blocks = 2/CU
#define GAMMA_F 5.0f
#define LN2_F   0.69314718f
#define LOG2E_F 1.44269504f

// Workspace layout (float units):
//  OFF_M  : Mq,Mk,Mv  (3 x 128x384 fp32)   M[i][m] = sum_j softplus(W[j][i]) * S[j][m]
//  OFF_C  : cq,ck,cv  (3 x 384 fp32)       c[m]    = sum_j b[j] * S[j][m]
//  OFF_WP2: delta-packed bf16 Wp (384x384 uint2): [i][m] = {lo:d0,hi:d1},{lo:d2}
//           d_r = bf16(softplus(Wp[r*384+m][i]) - ln2)
#define OFF_M    0
#define OFF_C    147456
#define OFF_WP2  148608   // 147456 uint2 = 294912 floats

__device__ __forceinline__ float softplusf(float x) {
    return fmaxf(x, 0.0f) + log1pf(__expf(-fabsf(x)));   // stable log1p(exp(x))
}
__device__ __forceinline__ unsigned short f2bf(float f) {
    __hip_bfloat16 h = __float2bfloat16(f);              // RNE
    return *reinterpret_cast<unsigned short*>(&h);
}
__device__ __forceinline__ float exp2_fast(float x) {
#if __has_builtin(__builtin_amdgcn_exp2f)
    return __builtin_amdgcn_exp2f(x);
#else
    return __expf(x * LN2_F);                            // exp(ln2*x) = 2^x
#endif
}

// ---------------- merged prep: grid 771 x 384
//  blocks [0,384)   : Wp delta-pack table
//  blocks [384,768) : M matrices
//  blocks [768,771) : c vectors
__global__ __launch_bounds__(384) void k_prep(const float* __restrict__ Wq, const float* __restrict__ Wk,
                                              const float* __restrict__ Wv, const float* __restrict__ Wp,
                                              const float* __restrict__ Sq, const float* __restrict__ Sk,
                                              const float* __restrict__ Sv, const float* __restrict__ bq,
                                              const float* __restrict__ bk, const float* __restrict__ bv,
                                              float* __restrict__ ws) {
    __shared__ float sw[DD3];
    int b = blockIdx.x, tid = threadIdx.x;
    if (b < 384) {                       // ---- Wp pack: idx in [0,147456)
        int idx = b * 384 + tid;
        int i = idx / DD3, m = idx % DD3;
        unsigned d0 = f2bf(softplusf(Wp[(0 * DD3 + m) * DD3 + i]) - LN2_F);
        unsigned d1 = f2bf(softplusf(Wp[(1 * DD3 + m) * DD3 + i]) - LN2_F);
        unsigned d2 = f2bf(softplusf(Wp[(2 * DD3 + m) * DD3 + i]) - LN2_F);
        uint2 u; u.x = d0 | (d1 << 16); u.y = d2;
        ((uint2*)(ws + OFF_WP2))[idx] = u;
    } else if (b < 768) {                // ---- M[i][m] for one (mat, i)
        int bb = b - 384;
        int mat = bb >> 7, i = bb & 127;
        const float* W = (mat == 0) ? Wq : (mat == 1 ? Wk : Wv);
        const float* S = (mat == 0) ? Sq : (mat == 1 ? Sk : Sv);
        int m = tid;
        sw[m] = softplusf(W[m * DD + i]);                // j = tid
        __syncthreads();
        const float4* sw4 = (const float4*)sw;
        float a0 = 0.f, a1 = 0.f, a2 = 0.f, a3 = 0.f;
        for (int j4 = 0; j4 < 96; ++j4) {
            float4 w = sw4[j4];
            int j = j4 * 4;
            a0 = fmaf(w.x, S[(j + 0) * DD3 + m], a0);
            a1 = fmaf(w.y, S[(j + 1) * DD3 + m], a1);
            a2 = fmaf(w.z, S[(j + 2) * DD3 + m], a2);
            a3 = fmaf(w.w, S[(j + 3) * DD3 + m], a3);
        }
        ws[OFF_M + mat * 49152 + i * DD3 + m] = (a0 + a1) + (a2 + a3);
    } else {                             // ---- c[m]
        int mat = b - 768;
        const float* S = (mat == 0) ? Sq : (mat == 1 ? Sk : Sv);
        const float* bb_ = (mat == 0) ? bq : (mat == 1 ? bk : bv);
        int m = tid;
        float a0 = 0.f, a1 = 0.f, a2 = 0.f, a3 = 0.f;
        for (int j4 = 0; j4 < 96; ++j4) {
            int j = j4 * 4;
            a0 = fmaf(bb_[j + 0], S[(j + 0) * DD3 + m], a0);
            a1 = fmaf(bb_[j + 1], S[(j + 1) * DD3 + m], a1);
            a2 = fmaf(bb_[j + 2], S[(j + 2) * DD3 + m], a2);
            a3 = fmaf(bb_[j + 3], S[(j + 3) * DD3 + m], a3);
        }
        ws[OFF_C + mat * DD3 + m] = (a0 + a1) + (a2 + a3);
    }
}

#define SIGROW(NQ, RS, AV) do {                                        \
        float e0 = exp2_fast((NQ) * kk.x);                             \
        float e1 = exp2_fast((NQ) * kk.y);                             \
        float e2 = exp2_fast((NQ) * kk.z);                             \
        float e3 = exp2_fast((NQ) * kk.w);                             \
        float s0 = __builtin_amdgcn_rcpf(1.0f + e0);                   \
        float s1 = __builtin_amdgcn_rcpf(1.0f + e1);                   \
        float s2 = __builtin_amdgcn_rcpf(1.0f + e2);                   \
        float s3 = __builtin_amdgcn_rcpf(1.0f + e3);                   \
        RS += (s0 + s1) + (s2 + s3);                                   \
        AV = fmaf(s0, vv.x, fmaf(s1, vv.y, fmaf(s2, vv.z, fmaf(s3, vv.w, AV)))); \
    } while (0)

// ---------------- fused main
__global__ __launch_bounds__(384, 3) void k_fused(const float* __restrict__ x,
                                                  const float* __restrict__ bp,
                                                  const float* __restrict__ gn,
                                                  const float* __restrict__ bn,
                                                  const float* __restrict__ ws,
                                                  float* __restrict__ out) {
    __shared__ float qkv[3 * TB * DD3];     // 18 KB  (Q | K | V, each [TB][384])
    __shared__ float att[TB * DD3];         // 6 KB
    __shared__ float red[32];
    __shared__ float ssum[TB], smu[TB], sinv[TB];

    int tid = threadIdx.x;                  // 0..383
    int tok0 = blockIdx.x * TB;
    const float* xb = x + (size_t)tok0 * DD3;

    // ---- phase 2: QKV projection. x read via wave-uniform global loads (no LDS).
#pragma unroll
    for (int mat = 0; mat < 3; ++mat) {
        const float* M = ws + OFF_M + mat * 49152;
        const float* xt0 = xb + 0 * DD3 + mat * DD;
        const float* xt1 = xb + 1 * DD3 + mat * DD;
        const float* xt2 = xb + 2 * DD3 + mat * DD;
        const float* xt3 = xb + 3 * DD3 + mat * DD;
        float a0 = 0.f, a1 = 0.f, a2 = 0.f, a3 = 0.f;
        for (int i = 0; i < DD; i += 4) {
            float m0 = M[(i + 0) * DD3 + tid];
            float m1 = M[(i + 1) * DD3 + tid];
            float m2 = M[(i + 2) * DD3 + tid];
            float m3 = M[(i + 3) * DD3 + tid];
            a0 = fmaf(xt0[i], m0, fmaf(xt0[i + 1], m1, fmaf(xt0[i + 2], m2, fmaf(xt0[i + 3], m3, a0))));
            a1 = fmaf(xt1[i], m0, fmaf(xt1[i + 1], m1, fmaf(xt1[i + 2], m2, fmaf(xt1[i + 3], m3, a1))));
            a2 = fmaf(xt2[i], m0, fmaf(xt2[i + 1], m1, fmaf(xt2[i + 2], m2, fmaf(xt2[i + 3], m3, a2))));
            a3 = fmaf(xt3[i], m0, fmaf(xt3[i + 1], m1, fmaf(xt3[i + 2], m2, fmaf(xt3[i + 3], m3, a3))));
        }
        float c = ws[OFF_C + mat * DD3 + tid];
        qkv[(mat * TB + 0) * DD3 + tid] = a0 + c;
        qkv[(mat * TB + 1) * DD3 + tid] = a1 + c;
        qkv[(mat * TB + 2) * DD3 + tid] = a2 + c;
        qkv[(mat * TB + 3) * DD3 + tid] = a3 + c;
    }
    __syncthreads();

    // ---- phase 3: sigmoid attention. Thread owns 4 rows {ts+96k} of ONE token:
    // per j4 only 2 broadcast b128 reads feed 16 sigmoids (4x less LDS than row-per-thread).
    {
        int t  = tid / 96;
        int ts = tid - t * 96;
        const float* Qt = qkv + t * DD3;
        float nq0 = Qt[ts +   0] * (-GAMMA_F * LOG2E_F);
        float nq1 = Qt[ts +  96] * (-GAMMA_F * LOG2E_F);
        float nq2 = Qt[ts + 192] * (-GAMMA_F * LOG2E_F);
        float nq3 = Qt[ts + 288] * (-GAMMA_F * LOG2E_F);
        const float4* K4 = (const float4*)(qkv + (TB + t) * DD3);
        const float4* V4 = (const float4*)(qkv + (2 * TB + t) * DD3);
        float rs0 = 0.f, rs1 = 0.f, rs2 = 0.f, rs3 = 0.f;
        float av0 = 0.f, av1 = 0.f, av2 = 0.f, av3 = 0.f;
        for (int j4 = 0; j4 < 96; ++j4) {
            float4 kk = K4[j4];
            float4 vv = V4[j4];
            SIGROW(nq0, rs0, av0);
            SIGROW(nq1, rs1, av1);
            SIGROW(nq2, rs2, av2);
            SIGROW(nq3, rs3, av3);
        }
        att[t * DD3 + ts +   0] = av0 * __builtin_amdgcn_rcpf(rs0 + 1e-8f);
        att[t * DD3 + ts +  96] = av1 * __builtin_amdgcn_rcpf(rs1 + 1e-8f);
        att[t * DD3 + ts + 192] = av2 * __builtin_amdgcn_rcpf(rs2 + 1e-8f);
        att[t * DD3 + ts + 288] = av3 * __builtin_amdgcn_rcpf(rs3 + 1e-8f);
    }
    __syncthreads();

    int wave = tid >> 6, lane = tid & 63;

    // ---- per-token sum of att (for the ln2 rank-1 fold in phase 4)
    {
        float s0 = att[0 * DD3 + tid];
        float s1 = att[1 * DD3 + tid];
        float s2 = att[2 * DD3 + tid];
        float s3 = att[3 * DD3 + tid];
#pragma unroll
        for (int off = 32; off; off >>= 1) {
            s0 += __shfl_down(s0, off, 64);
            s1 += __shfl_down(s1, off, 64);
            s2 += __shfl_down(s2, off, 64);
            s3 += __shfl_down(s3, off, 64);
        }
        if (lane == 0) {
            red[0 * 8 + wave] = s0; red[1 * 8 + wave] = s1;
            red[2 * 8 + wave] = s2; red[3 * 8 + wave] = s3;
        }
        __syncthreads();
        if (tid < TB) {
            float a = 0.f;
            for (int w = 0; w < 6; ++w) a += red[tid * 8 + w];
            ssum[tid] = a;
        }
        __syncthreads();
    }

    // ---- phase 4: h[t][o] = bp[o] + ln2*ssum[t] + sum_i att[t][i]*delta[i][o]
    const uint2* wp2 = (const uint2*)(ws + OFF_WP2);
    float acc[3][TB];
    {
        float bp0 = bp[tid], bp1 = bp[tid + DD3], bp2 = bp[tid + 2 * DD3];
#pragma unroll
        for (int t = 0; t < TB; ++t) {
            float base = LN2_F * ssum[t];
            acc[0][t] = bp0 + base;
            acc[1][t] = bp1 + base;
            acc[2][t] = bp2 + base;
        }
    }
    const float4* att4 = (const float4*)att;
    for (int i4 = 0; i4 < 96; ++i4) {
        float4 a0 = att4[0 * 96 + i4];
        float4 a1 = att4[1 * 96 + i4];
        float4 a2 = att4[2 * 96 + i4];
        float4 a3 = att4[3 * 96 + i4];
        const float* af0 = (const float*)&a0;
        const float* af1 = (const float*)&a1;
        const float* af2 = (const float*)&a2;
        const float* af3 = (const float*)&a3;
#pragma unroll
        for (int e = 0; e < 4; ++e) {
            uint2 u = wp2[(i4 * 4 + e) * DD3 + tid];
            float w0 = __uint_as_float(u.x << 16);
            float w1 = __uint_as_float(u.x & 0xffff0000u);
            float w2 = __uint_as_float(u.y << 16);
            acc[0][0] = fmaf(af0[e], w0, acc[0][0]);
            acc[1][0] = fmaf(af0[e], w1, acc[1][0]);
            acc[2][0] = fmaf(af0[e], w2, acc[2][0]);
            acc[0][1] = fmaf(af1[e], w0, acc[0][1]);
            acc[1][1] = fmaf(af1[e], w1, acc[1][1]);
            acc[2][1] = fmaf(af1[e], w2, acc[2][1]);
            acc[0][2] = fmaf(af2[e], w0, acc[0][2]);
            acc[1][2] = fmaf(af2[e], w1, acc[1][2]);
            acc[2][2] = fmaf(af2[e], w2, acc[2][2]);
            acc[0][3] = fmaf(af3[e], w0, acc[0][3]);
            acc[1][3] = fmaf(af3[e], w1, acc[1][3]);
            acc[2][3] = fmaf(af3[e], w2, acc[2][3]);
        }
    }

    // ---- phase 5: two-pass LayerNorm (mu first; then var of deviations)
#pragma unroll
    for (int t = 0; t < TB; ++t) {
        float s = acc[0][t] + acc[1][t] + acc[2][t];
#pragma unroll
        for (int off = 32; off; off >>= 1) s += __shfl_down(s, off, 64);
        if (lane == 0) red[t * 8 + wave] = s;
    }
    __syncthreads();
    if (tid < TB) {
        float a = 0.f;
        for (int w = 0; w < 6; ++w) a += red[tid * 8 + w];
        smu[tid] = a * (1.0f / 1152.0f);
    }
    __syncthreads();
#pragma unroll
    for (int t = 0; t < TB; ++t) {
        float mu = smu[t];
        acc[0][t] -= mu; acc[1][t] -= mu; acc[2][t] -= mu;
        float s = fmaf(acc[0][t], acc[0][t], fmaf(acc[1][t], acc[1][t], acc[2][t] * acc[2][t]));
#pragma unroll
        for (int off = 32; off; off >>= 1) s += __shfl_down(s, off, 64);
        if (lane == 0) red[t * 8 + wave] = s;
    }
    __syncthreads();
    if (tid < TB) {
        float b = 0.f;
        for (int w = 0; w < 6; ++w) b += red[tid * 8 + w];
        sinv[tid] = __builtin_amdgcn_rsqf(b * (1.0f / 1152.0f) + 1e-5f);
    }
    __syncthreads();
    float g0 = gn[tid], g1 = gn[tid + DD3], g2 = gn[tid + 2 * DD3];
    float b0 = bn[tid], b1 = bn[tid + DD3], b2 = bn[tid + 2 * DD3];
#pragma unroll
    for (int t = 0; t < TB; ++t) {
        float inv = sinv[t];
        size_t base = (size_t)(tok0 + t) * DD9;
        out[base + tid]           = fmaf(acc[0][t] * inv, g0, b0);
        out[base + tid + DD3]     = fmaf(acc[1][t] * inv, g1, b1);
        out[base + tid + 2 * DD3] = fmaf(acc[2][t] * inv, g2, b2);
    }
}

extern "C" void kernel_launch(void* const* d_in, const int* in_sizes, int n_in,
                              void* d_out, int out_size, void* d_ws, size_t ws_size,
                              hipStream_t stream) {
    const float* x  = (const float*)d_in[0];
    const float* Wq = (const float*)d_in[1];
    const float* bq = (const float*)d_in[2];
    const float* Sq = (const float*)d_in[3];
    const float* Wk = (const float*)d_in[4];
    const float* bk = (const float*)d_in[5];
    const float* Sk = (const float*)d_in[6];
    const float* Wv = (const float*)d_in[7];
    const float* bv = (const float*)d_in[8];
    const float* Sv = (const float*)d_in[9];
    const float* Wp = (const float*)d_in[10];
    const float* bp = (const float*)d_in[11];
    const float* gn = (const float*)d_in[12];
    const float* bn = (const float*)d_in[13];
    float* out = (float*)d_out;
    float* ws  = (float*)d_ws;

    hipLaunchKernelGGL(k_prep, dim3(771), dim3(384), 0, stream,
                       Wq, Wk, Wv, Wp, Sq, Sk, Sv, bq, bk, bv, ws);
    hipLaunchKernelGGL(k_fused, dim3(NTOK / TB), dim3(384), 0, stream, x, bp, gn, bn, ws, out);
}

// Round 7
// 155.526 us; speedup vs baseline: 1.5095x; 1.0250x over previous
//
#include <hip/hip_runtime.h>
#include <hip/hip_bf16.h>
#include <math.h>

// Problem geometry (B=2, T=1024, D=384 -> d=128, D3=384, D9=1152)
#define NTOK  2048
#define DD    128
#define DD3   384
#define DD9   1152
#define TB    2          // tokens per block -> 1024 blocks = 4/CU (grid was the occupancy cap)
#define GAMMA_F 5.0f
#define LN2_F   0.69314718f
#define LOG2E_F 1.44269504f

// Workspace layout (float units):
//  OFF_M  : Mq,Mk,Mv  (3 x 128x384 fp32)   M[i][m] = sum_j softplus(W[j][i]) * S[j][m]
//  OFF_C  : cq,ck,cv  (3 x 384 fp32)       c[m]    = sum_j b[j] * S[j][m]
//  OFF_WP2: delta-packed bf16 Wp (384x384 uint2): [i][m] = {lo:d0,hi:d1},{lo:d2}
//           d_r = bf16(softplus(Wp[r*384+m][i]) - ln2)
#define OFF_M    0
#define OFF_C    147456
#define OFF_WP2  148608   // 147456 uint2 = 294912 floats

typedef __attribute__((ext_vector_type(2))) float f32x2;

__device__ __forceinline__ float softplusf(float x) {
    return fmaxf(x, 0.0f) + log1pf(__expf(-fabsf(x)));   // stable log1p(exp(x))
}
__device__ __forceinline__ unsigned short f2bf(float f) {
    __hip_bfloat16 h = __float2bfloat16(f);              // RNE
    return *reinterpret_cast<unsigned short*>(&h);
}
__device__ __forceinline__ float exp2_fast(float x) {
#if __has_builtin(__builtin_amdgcn_exp2f)
    return __builtin_amdgcn_exp2f(x);
#else
    return __expf(x * LN2_F);
#endif
}

// ---------------- merged prep: grid 771 x 384 (verbatim from round-5 pass)
//  blocks [0,384)   : Wp delta-pack table
//  blocks [384,768) : M matrices
//  blocks [768,771) : c vectors
__global__ __launch_bounds__(384) void k_prep(const float* __restrict__ Wq, const float* __restrict__ Wk,
                                              const float* __restrict__ Wv, const float* __restrict__ Wp,
                                              const float* __restrict__ Sq, const float* __restrict__ Sk,
                                              const float* __restrict__ Sv, const float* __restrict__ bq,
                                              const float* __restrict__ bk, const float* __restrict__ bv,
                                              float* __restrict__ ws) {
    __shared__ float sw[DD3];
    int b = blockIdx.x, tid = threadIdx.x;
    if (b < 384) {                       // ---- Wp pack: idx in [0,147456)
        int idx = b * 384 + tid;
        int i = idx / DD3, m = idx % DD3;
        unsigned d0 = f2bf(softplusf(Wp[(0 * DD3 + m) * DD3 + i]) - LN2_F);
        unsigned d1 = f2bf(softplusf(Wp[(1 * DD3 + m) * DD3 + i]) - LN2_F);
        unsigned d2 = f2bf(softplusf(Wp[(2 * DD3 + m) * DD3 + i]) - LN2_F);
        uint2 u; u.x = d0 | (d1 << 16); u.y = d2;
        ((uint2*)(ws + OFF_WP2))[idx] = u;
    } else if (b < 768) {                // ---- M[i][m] for one (mat, i)
        int bb = b - 384;
        int mat = bb >> 7, i = bb & 127;
        const float* W = (mat == 0) ? Wq : (mat == 1 ? Wk : Wv);
        const float* S = (mat == 0) ? Sq : (mat == 1 ? Sk : Sv);
        int m = tid;
        sw[m] = softplusf(W[m * DD + i]);                // j = tid
        __syncthreads();
        const float4* sw4 = (const float4*)sw;
        float a0 = 0.f, a1 = 0.f, a2 = 0.f, a3 = 0.f;
        for (int j4 = 0; j4 < 96; ++j4) {
            float4 w = sw4[j4];
            int j = j4 * 4;
            a0 = fmaf(w.x, S[(j + 0) * DD3 + m], a0);
            a1 = fmaf(w.y, S[(j + 1) * DD3 + m], a1);
            a2 = fmaf(w.z, S[(j + 2) * DD3 + m], a2);
            a3 = fmaf(w.w, S[(j + 3) * DD3 + m], a3);
        }
        ws[OFF_M + mat * 49152 + i * DD3 + m] = (a0 + a1) + (a2 + a3);
    } else {                             // ---- c[m]
        int mat = b - 768;
        const float* S = (mat == 0) ? Sq : (mat == 1 ? Sk : Sv);
        const float* bb_ = (mat == 0) ? bq : (mat == 1 ? bk : bv);
        int m = tid;
        float a0 = 0.f, a1 = 0.f, a2 = 0.f, a3 = 0.f;
        for (int j4 = 0; j4 < 96; ++j4) {
            int j = j4 * 4;
            a0 = fmaf(bb_[j + 0], S[(j + 0) * DD3 + m], a0);
            a1 = fmaf(bb_[j + 1], S[(j + 1) * DD3 + m], a1);
            a2 = fmaf(bb_[j + 2], S[(j + 2) * DD3 + m], a2);
            a3 = fmaf(bb_[j + 3], S[(j + 3) * DD3 + m], a3);
        }
        ws[OFF_C + mat * DD3 + m] = (a0 + a1) + (a2 + a3);
    }
}

#define SIGROW(NQ, RS, AV) do {                                        \
        float e0 = exp2_fast((NQ) * kk.x);                             \
        float e1 = exp2_fast((NQ) * kk.y);                             \
        float e2 = exp2_fast((NQ) * kk.z);                             \
        float e3 = exp2_fast((NQ) * kk.w);                             \
        float s0 = __builtin_amdgcn_rcpf(1.0f + e0);                   \
        float s1 = __builtin_amdgcn_rcpf(1.0f + e1);                   \
        float s2 = __builtin_amdgcn_rcpf(1.0f + e2);                   \
        float s3 = __builtin_amdgcn_rcpf(1.0f + e3);                   \
        RS += (s0 + s1) + (s2 + s3);                                   \
        AV = fmaf(s0, vv.x, fmaf(s1, vv.y, fmaf(s2, vv.z, fmaf(s3, vv.w, AV)))); \
    } while (0)

// ---------------- fused main (TB=2)
__global__ __launch_bounds__(384, 6) void k_fused(const float* __restrict__ x,
                                                  const float* __restrict__ bp,
                                                  const float* __restrict__ gn,
                                                  const float* __restrict__ bn,
                                                  const float* __restrict__ ws,
                                                  float* __restrict__ out) {
    __shared__ float qkv[3 * TB * DD3];     // 9 KB  (Q | K | V, each [TB][384])
    __shared__ float att[TB * DD3];         // 3 KB
    __shared__ float red[16];
    __shared__ float ssum[TB], smu[TB], sinv[TB];

    int tid = threadIdx.x;                  // 0..383
    int tok0 = blockIdx.x * TB;
    const float* xb = x + (size_t)tok0 * DD3;

    // ---- phase 2: QKV projection. x via wave-uniform (scalar) global loads.
#pragma unroll
    for (int mat = 0; mat < 3; ++mat) {
        const float* M = ws + OFF_M + mat * 49152;
        const float* xt0 = xb + 0 * DD3 + mat * DD;
        const float* xt1 = xb + 1 * DD3 + mat * DD;
        float a0 = 0.f, a1 = 0.f;
        for (int i = 0; i < DD; i += 4) {
            float m0 = M[(i + 0) * DD3 + tid];
            float m1 = M[(i + 1) * DD3 + tid];
            float m2 = M[(i + 2) * DD3 + tid];
            float m3 = M[(i + 3) * DD3 + tid];
            a0 = fmaf(xt0[i], m0, fmaf(xt0[i + 1], m1, fmaf(xt0[i + 2], m2, fmaf(xt0[i + 3], m3, a0))));
            a1 = fmaf(xt1[i], m0, fmaf(xt1[i + 1], m1, fmaf(xt1[i + 2], m2, fmaf(xt1[i + 3], m3, a1))));
        }
        float c = ws[OFF_C + mat * DD3 + tid];
        qkv[(mat * TB + 0) * DD3 + tid] = a0 + c;
        qkv[(mat * TB + 1) * DD3 + tid] = a1 + c;
    }
    __syncthreads();

    // ---- phase 3: sigmoid attention. Thread owns rows {ts, ts+192} of ONE token.
    {
        int t  = tid / 192;                 // wave-uniform (192 = 3 waves)
        int ts = tid - t * 192;
        const float* Qt = qkv + t * DD3;
        float nq0 = Qt[ts]       * (-GAMMA_F * LOG2E_F);
        float nq1 = Qt[ts + 192] * (-GAMMA_F * LOG2E_F);
        const float4* K4 = (const float4*)(qkv + (TB + t) * DD3);
        const float4* V4 = (const float4*)(qkv + (2 * TB + t) * DD3);
        float rs0 = 0.f, rs1 = 0.f, av0 = 0.f, av1 = 0.f;
        for (int j4 = 0; j4 < 96; ++j4) {
            float4 kk = K4[j4];
            float4 vv = V4[j4];
            SIGROW(nq0, rs0, av0);
            SIGROW(nq1, rs1, av1);
        }
        att[t * DD3 + ts]       = av0 * __builtin_amdgcn_rcpf(rs0 + 1e-8f);
        att[t * DD3 + ts + 192] = av1 * __builtin_amdgcn_rcpf(rs1 + 1e-8f);
    }
    __syncthreads();

    int wave = tid >> 6, lane64 = tid & 63;

    // ---- per-token sum of att (ln2 rank-1 fold)
    {
        float s0 = att[0 * DD3 + tid];
        float s1 = att[1 * DD3 + tid];
#pragma unroll
        for (int off = 32; off; off >>= 1) {
            s0 += __shfl_down(s0, off, 64);
            s1 += __shfl_down(s1, off, 64);
        }
        if (lane64 == 0) { red[wave] = s0; red[8 + wave] = s1; }
        __syncthreads();
        if (tid < TB) {
            float a = 0.f;
            for (int w = 0; w < 6; ++w) a += red[tid * 8 + w];
            ssum[tid] = a;
        }
        __syncthreads();
    }

    // ---- phase 4: h[t][o] = bp[o] + ln2*ssum[t] + sum_i att[t][i]*delta[i][o]
    // token-pair packed fp32 (v_pk_fma_f32); per-token FMA chain order identical to round 5.
    const uint2* wp2 = (const uint2*)(ws + OFF_WP2);
    f32x2 acc2[3];
    {
        float bp0 = bp[tid], bp1 = bp[tid + DD3], bp2 = bp[tid + 2 * DD3];
        float b0 = LN2_F * ssum[0], b1 = LN2_F * ssum[1];
        acc2[0] = (f32x2){bp0 + b0, bp0 + b1};
        acc2[1] = (f32x2){bp1 + b0, bp1 + b1};
        acc2[2] = (f32x2){bp2 + b0, bp2 + b1};
    }
    const float4* att4 = (const float4*)att;
    for (int i4 = 0; i4 < 96; ++i4) {
        float4 a0 = att4[0 * 96 + i4];
        float4 a1 = att4[1 * 96 + i4];
        const float* af0 = (const float*)&a0;
        const float* af1 = (const float*)&a1;
#pragma unroll
        for (int e = 0; e < 4; ++e) {
            uint2 u = wp2[(i4 * 4 + e) * DD3 + tid];
            float w0 = __uint_as_float(u.x << 16);
            float w1 = __uint_as_float(u.x & 0xffff0000u);
            float w2 = __uint_as_float(u.y << 16);
            f32x2 a01 = (f32x2){af0[e], af1[e]};
            acc2[0] = __builtin_elementwise_fma(a01, (f32x2){w0, w0}, acc2[0]);
            acc2[1] = __builtin_elementwise_fma(a01, (f32x2){w1, w1}, acc2[1]);
            acc2[2] = __builtin_elementwise_fma(a01, (f32x2){w2, w2}, acc2[2]);
        }
    }
    float av_[3][TB] = {{acc2[0].x, acc2[0].y}, {acc2[1].x, acc2[1].y}, {acc2[2].x, acc2[2].y}};

    // ---- phase 5: two-pass LayerNorm (mu first; then var of deviations)
#pragma unroll
    for (int t = 0; t < TB; ++t) {
        float s = av_[0][t] + av_[1][t] + av_[2][t];
#pragma unroll
        for (int off = 32; off; off >>= 1) s += __shfl_down(s, off, 64);
        if (lane64 == 0) red[t * 8 + wave] = s;
    }
    __syncthreads();
    if (tid < TB) {
        float a = 0.f;
        for (int w = 0; w < 6; ++w) a += red[tid * 8 + w];
        smu[tid] = a * (1.0f / 1152.0f);
    }
    __syncthreads();
#pragma unroll
    for (int t = 0; t < TB; ++t) {
        float mu = smu[t];
        av_[0][t] -= mu; av_[1][t] -= mu; av_[2][t] -= mu;
        float s = fmaf(av_[0][t], av_[0][t], fmaf(av_[1][t], av_[1][t], av_[2][t] * av_[2][t]));
#pragma unroll
        for (int off = 32; off; off >>= 1) s += __shfl_down(s, off, 64);
        if (lane64 == 0) red[t * 8 + wave] = s;
    }
    __syncthreads();
    if (tid < TB) {
        float b = 0.f;
        for (int w = 0; w < 6; ++w) b += red[tid * 8 + w];
        sinv[tid] = __builtin_amdgcn_rsqf(b * (1.0f / 1152.0f) + 1e-5f);
    }
    __syncthreads();
    float g0 = gn[tid], g1 = gn[tid + DD3], g2 = gn[tid + 2 * DD3];
    float b0 = bn[tid], b1 = bn[tid + DD3], b2 = bn[tid + 2 * DD3];
#pragma unroll
    for (int t = 0; t < TB; ++t) {
        float inv = sinv[t];
        size_t base = (size_t)(tok0 + t) * DD9;
        out[base + tid]           = fmaf(av_[0][t] * inv, g0, b0);
        out[base + tid + DD3]     = fmaf(av_[1][t] * inv, g1, b1);
        out[base + tid + 2 * DD3] = fmaf(av_[2][t] * inv, g2, b2);
    }
}

extern "C" void kernel_launch(void* const* d_in, const int* in_sizes, int n_in,
                              void* d_out, int out_size, void* d_ws, size_t ws_size,
                              hipStream_t stream) {
    const float* x  = (const float*)d_in[0];
    const float* Wq = (const float*)d_in[1];
    const float* bq = (const float*)d_in[2];
    const float* Sq = (const float*)d_in[3];
    const float* Wk = (const float*)d_in[4];
    const float* bk = (const float*)d_in[5];
    const float* Sk = (const float*)d_in[6];
    const float* Wv = (const float*)d_in[7];
    const float* bv = (const float*)d_in[8];
    const float* Sv = (const float*)d_in[9];
    const float* Wp = (const float*)d_in[10];
    const float* bp = (const float*)d_in[11];
    const float* gn = (const float*)d_in[12];
    const float* bn = (const float*)d_in[13];
    float* out = (float*)d_out;
    float* ws  = (float*)d_ws;

    hipLaunchKernelGGL(k_prep, dim3(771), dim3(384), 0, stream,
                       Wq, Wk, Wv, Wp, Sq, Sk, Sv, bq, bk, bv, ws);
    hipLaunchKernelGGL(k_fused, dim3(NTOK / TB), dim3(384), 0, stream, x, bp, gn, bn, ws, out);
}